// Round 1
// baseline (1562.404 us; speedup 1.0000x reference)
//
#include <hip/hip_runtime.h>

#define B_ 8
#define L_ 1024
#define HID_ 1024
#define D_ 64
#define KS_ 1032

typedef short bf16x8 __attribute__((ext_vector_type(8)));
typedef float f32x4 __attribute__((ext_vector_type(4)));

__device__ inline short f2bf(float f) {
    unsigned u = __builtin_bit_cast(unsigned, f);
    unsigned r = (u + 0x7fffu + ((u >> 16) & 1u)) >> 16;   // RNE
    return (short)r;
}
__device__ inline float bf2f(short h) {
    unsigned u = ((unsigned)(unsigned short)h) << 16;
    return __builtin_bit_cast(float, u);
}

// ---------------- K1: projections.
// q -> hi/lo bf16 of 0.125*(query@Wq+bq)   (scale folded in: both score terms use it)
// k -> hi/lo bf16 of (key@Wk+bk)           (hi+lo recovers fp32 to ~2^-17)
// v -> fp32
__global__ __launch_bounds__(256) void proj_kernel(
    const float* __restrict__ query, const float* __restrict__ key, const float* __restrict__ value,
    const float* __restrict__ Wq, const float* __restrict__ bq,
    const float* __restrict__ Wk, const float* __restrict__ bk,
    const float* __restrict__ Wv, const float* __restrict__ bv,
    unsigned short* __restrict__ qhi, unsigned short* __restrict__ qlo,
    unsigned short* __restrict__ khi, unsigned short* __restrict__ klo,
    float* __restrict__ vp)
{
    const int which = blockIdx.y;
    const float* in   = which == 0 ? query : (which == 1 ? key : value);
    const float* W    = which == 0 ? Wq : (which == 1 ? Wk : Wv);
    const float* bias = which == 0 ? bq : (which == 1 ? bk : bv);

    __shared__ float Xs[64][68];
    __shared__ float Ws[64][64];

    const int t  = threadIdx.x;
    const int tx = t & 15;
    const int ty = t >> 4;
    const int r0 = blockIdx.x * 64;

    float acc[4][4] = {};
    for (int kk = 0; kk < HID_; kk += 64) {
        {
            const int r  = t >> 4;
            const int c4 = t & 15;
            #pragma unroll
            for (int i = 0; i < 4; i++) {
                float4 x = *(const float4*)(in + (size_t)(r0 + r + 16 * i) * HID_ + kk + 4 * c4);
                *(float4*)(&Xs[r + 16 * i][4 * c4]) = x;
                float4 w = *(const float4*)(W + (size_t)(kk + r + 16 * i) * D_ + 4 * c4);
                *(float4*)(&Ws[r + 16 * i][4 * c4]) = w;
            }
        }
        __syncthreads();
        #pragma unroll 8
        for (int k = 0; k < 64; k++) {
            float4 b4 = *(const float4*)(&Ws[k][4 * tx]);
            #pragma unroll
            for (int i = 0; i < 4; i++) {
                float a = Xs[4 * ty + i][k];
                acc[i][0] += a * b4.x;
                acc[i][1] += a * b4.y;
                acc[i][2] += a * b4.z;
                acc[i][3] += a * b4.w;
            }
        }
        __syncthreads();
    }
    float4 bb = *(const float4*)(bias + 4 * tx);
    if (which == 2) {
        #pragma unroll
        for (int i = 0; i < 4; i++) {
            float4 o;
            o.x = acc[i][0] + bb.x; o.y = acc[i][1] + bb.y;
            o.z = acc[i][2] + bb.z; o.w = acc[i][3] + bb.w;
            *(float4*)(vp + (size_t)(r0 + 4 * ty + i) * D_ + 4 * tx) = o;
        }
    } else {
        const float sgain = (which == 0) ? 0.125f : 1.0f;
        unsigned short* hid = (which == 0) ? qhi : khi;
        unsigned short* lod = (which == 0) ? qlo : klo;
        #pragma unroll
        for (int i = 0; i < 4; i++) {
            float v0 = sgain * (acc[i][0] + bb.x);
            float v1 = sgain * (acc[i][1] + bb.y);
            float v2 = sgain * (acc[i][2] + bb.z);
            float v3 = sgain * (acc[i][3] + bb.w);
            short h0 = f2bf(v0), h1 = f2bf(v1), h2 = f2bf(v2), h3 = f2bf(v3);
            ushort4 hv, lv;
            hv.x = (unsigned short)h0; hv.y = (unsigned short)h1;
            hv.z = (unsigned short)h2; hv.w = (unsigned short)h3;
            lv.x = (unsigned short)f2bf(v0 - bf2f(h0));
            lv.y = (unsigned short)f2bf(v1 - bf2f(h1));
            lv.z = (unsigned short)f2bf(v2 - bf2f(h2));
            lv.w = (unsigned short)f2bf(v3 - bf2f(h3));
            size_t off = (size_t)(r0 + 4 * ty + i) * D_ + 4 * tx;
            *(ushort4*)(hid + off) = hv;
            *(ushort4*)(lod + off) = lv;
        }
    }
}

// ---------------- K2: fully fused attention.
// Per block: 2 q rows x all 8 batches.  LDS sc[2][8][1032] fp32 scores.
// P1: s2 = kb_bf16 . (qhi+qlo)  via MFMA (B rows = (b,hi/lo) pairs, 16/16 cols used)
// P2: s1 += (khi+klo).(qhi+qlo) via MFMA (fp32-accurate attn1, kp from L2)
// P3: mask + softmax (weights stay in LDS)
// P4: out = w.(vp + vb)  (vb streamed from HBM, vp L2-resident)
__global__ __launch_bounds__(512, 4) void mega_kernel(
    const float* __restrict__ kb, const float* __restrict__ vb,
    const float* __restrict__ vp,
    const unsigned short* __restrict__ qhi, const unsigned short* __restrict__ qlo,
    const unsigned short* __restrict__ khi, const unsigned short* __restrict__ klo,
    const int* __restrict__ mask, float* __restrict__ out)
{
    __shared__ float sc[2 * 8 * KS_];            // 66048 B; aliased for partials in P4
    __shared__ unsigned short qb2[2 * 16 * D_];  // [q][(b,hl)][d] bf16, 4 KB
    const int t = threadIdx.x;
    const int wave = t >> 6, lane = t & 63;
    const int lr = lane & 15, lg = lane >> 4;
    const int q0 = blockIdx.x * 2;

    // prologue: build B-operand rows: row 2b+0 = qhi[b], row 2b+1 = qlo[b]
    {
        int d4 = t & 15, row = (t >> 4) & 15, q = t >> 8;
        int b = row >> 1;
        const unsigned short* src = (row & 1) ? qlo : qhi;
        ushort4 v = *(const ushort4*)(src + ((size_t)b * L_ + q0 + q) * D_ + 4 * d4);
        *(ushort4*)&qb2[(q * 16 + row) * D_ + 4 * d4] = v;
    }
    __syncthreads();

    // ---- P1: attn2 (kb term), streams kb from HBM
    for (int jj = 0; jj < 16; jj++) {
        int job = wave + jj * 8;                  // (q, ktile)
        int q = job >> 6, k0 = (job & 63) * 16;
        const float* abase = kb + ((size_t)(q0 + q) * L_ + k0 + lr) * D_ + lg * 8;
        f32x4 acc = {0.f, 0.f, 0.f, 0.f};
        #pragma unroll
        for (int h = 0; h < 2; h++) {
            float4 x0 = *(const float4*)(abase + h * 32);
            float4 x1 = *(const float4*)(abase + h * 32 + 4);
            bf16x8 a;
            a[0] = f2bf(x0.x); a[1] = f2bf(x0.y); a[2] = f2bf(x0.z); a[3] = f2bf(x0.w);
            a[4] = f2bf(x1.x); a[5] = f2bf(x1.y); a[6] = f2bf(x1.z); a[7] = f2bf(x1.w);
            bf16x8 qf = *(const bf16x8*)&qb2[(q * 16 + lr) * D_ + h * 32 + lg * 8];
            acc = __builtin_amdgcn_mfma_f32_16x16x32_bf16(a, qf, acc, 0, 0, 0);
        }
        // col 2b = kb.qhi, col 2b+1 = kb.qlo -> sum adjacent cols
        float s0 = acc[0] + __shfl_xor(acc[0], 1);
        float s1 = acc[1] + __shfl_xor(acc[1], 1);
        float s2 = acc[2] + __shfl_xor(acc[2], 1);
        float s3 = acc[3] + __shfl_xor(acc[3], 1);
        if (!(lane & 1)) {
            int b = lr >> 1;
            float* dst = &sc[(q * 8 + b) * KS_ + k0 + lg * 4];
            dst[0] = s0; dst[1] = s1; dst[2] = s2; dst[3] = s3;
        }
    }
    __syncthreads();

    // ---- P2: attn1 (content term), kp hi/lo from L2, fp32-accurate
    {
        bf16x8 qf[2][2];
        #pragma unroll
        for (int q = 0; q < 2; q++)
            #pragma unroll
            for (int s = 0; s < 2; s++)
                qf[q][s] = *(const bf16x8*)&qb2[(q * 16 + lr) * D_ + s * 32 + lg * 8];

        int job = wave;
        size_t off0 = ((size_t)((job >> 6) & 7) * L_ + (job & 63) * 16 + lr) * D_ + lg * 8;
        bf16x8 nh0 = *(const bf16x8*)(khi + off0);
        bf16x8 nh1 = *(const bf16x8*)(khi + off0 + 32);
        bf16x8 nl0 = *(const bf16x8*)(klo + off0);
        bf16x8 nl1 = *(const bf16x8*)(klo + off0 + 32);
        for (int jj = 0; jj < 128; jj++) {
            int q = job >> 9, b = (job >> 6) & 7, k0 = (job & 63) * 16;
            bf16x8 ah0 = nh0, ah1 = nh1, al0 = nl0, al1 = nl1;
            int nj = job + 8;
            if (jj < 127) {                       // prefetch next tile (hides L2 latency)
                size_t noff = ((size_t)((nj >> 6) & 7) * L_ + (nj & 63) * 16 + lr) * D_ + lg * 8;
                nh0 = *(const bf16x8*)(khi + noff);
                nh1 = *(const bf16x8*)(khi + noff + 32);
                nl0 = *(const bf16x8*)(klo + noff);
                nl1 = *(const bf16x8*)(klo + noff + 32);
            }
            f32x4 acc = {0.f, 0.f, 0.f, 0.f};
            acc = __builtin_amdgcn_mfma_f32_16x16x32_bf16(ah0, qf[q][0], acc, 0, 0, 0);
            acc = __builtin_amdgcn_mfma_f32_16x16x32_bf16(al0, qf[q][0], acc, 0, 0, 0);
            acc = __builtin_amdgcn_mfma_f32_16x16x32_bf16(ah1, qf[q][1], acc, 0, 0, 0);
            acc = __builtin_amdgcn_mfma_f32_16x16x32_bf16(al1, qf[q][1], acc, 0, 0, 0);
            float s0 = acc[0] + __shfl_xor(acc[0], 1);
            float s1 = acc[1] + __shfl_xor(acc[1], 1);
            float s2 = acc[2] + __shfl_xor(acc[2], 1);
            float s3 = acc[3] + __shfl_xor(acc[3], 1);
            if (lr == 2 * b) {                    // cols (2b,2b+1) hold this batch's scores
                float4* dst = (float4*)&sc[(q * 8 + b) * KS_ + k0 + lg * 4];
                float4 cur = *dst;
                cur.x += s0; cur.y += s1; cur.z += s2; cur.w += s3;
                *dst = cur;
            }
            job = nj;
        }
    }
    __syncthreads();

    // ---- P3: mask + softmax per (q,b) row; weights stay in LDS only
    #pragma unroll
    for (int rr = 0; rr < 2; rr++) {
        int r = wave + rr * 8;                    // r = q*8 + b
        int b = r & 7;
        float* rowp = &sc[r * KS_];
        const int* mrow = mask + b * L_;
        float4 x[4];
        float mx = -1e30f;
        #pragma unroll
        for (int j = 0; j < 4; j++) {
            x[j] = *(const float4*)&rowp[lane * 4 + 256 * j];
            int4 mm = *(const int4*)&mrow[lane * 4 + 256 * j];
            x[j].x = mm.x ? x[j].x : -1e9f;
            x[j].y = mm.y ? x[j].y : -1e9f;
            x[j].z = mm.z ? x[j].z : -1e9f;
            x[j].w = mm.w ? x[j].w : -1e9f;
            mx = fmaxf(mx, fmaxf(fmaxf(x[j].x, x[j].y), fmaxf(x[j].z, x[j].w)));
        }
        #pragma unroll
        for (int off = 32; off; off >>= 1) mx = fmaxf(mx, __shfl_xor(mx, off));
        float s = 0.f;
        #pragma unroll
        for (int j = 0; j < 4; j++) {
            x[j].x = __expf(x[j].x - mx); x[j].y = __expf(x[j].y - mx);
            x[j].z = __expf(x[j].z - mx); x[j].w = __expf(x[j].w - mx);
            s += x[j].x + x[j].y + x[j].z + x[j].w;
        }
        #pragma unroll
        for (int off = 32; off; off >>= 1) s += __shfl_xor(s, off);
        float inv = 1.0f / s;
        #pragma unroll
        for (int j = 0; j < 4; j++) {
            x[j].x *= inv; x[j].y *= inv; x[j].z *= inv; x[j].w *= inv;
            *(float4*)&rowp[lane * 4 + 256 * j] = x[j];
        }
    }
    __syncthreads();

    // ---- P4: out = w.(vp + vb); vb streamed (HBM), vp from L2.  No pv_kernel.
    {
        const int q   = wave >> 2;
        const int kqi = wave & 3;
        const int kq  = kqi * 256;
        const int kl  = lane >> 4;
        const int d4  = lane & 15;
        float acc[8][4] = {};
        const float* vbbase = vb + ((size_t)(q0 + q) * L_ + kq + kl) * D_ + d4 * 4;
        const float* vpbase = vp + ((size_t)(kq + kl)) * D_ + d4 * 4;
        for (int j = 0; j < 64; j++) {
            float4 vb4 = *(const float4*)(vbbase + (size_t)j * 4 * D_);
            float4 vp4[8];
            #pragma unroll
            for (int b = 0; b < 8; b++)
                vp4[b] = *(const float4*)(vpbase + (size_t)b * L_ * D_ + (size_t)j * 4 * D_);
            int k = kq + j * 4 + kl;
            #pragma unroll
            for (int b = 0; b < 8; b++) {
                float wgt = sc[(q * 8 + b) * KS_ + k];
                acc[b][0] += wgt * vb4.x;    acc[b][1] += wgt * vb4.y;
                acc[b][2] += wgt * vb4.z;    acc[b][3] += wgt * vb4.w;
                acc[b][0] += wgt * vp4[b].x; acc[b][1] += wgt * vp4[b].y;
                acc[b][2] += wgt * vp4[b].z; acc[b][3] += wgt * vp4[b].w;
            }
        }
        #pragma unroll
        for (int b = 0; b < 8; b++)
            #pragma unroll
            for (int j = 0; j < 4; j++) {
                float v = acc[b][j];
                v += __shfl_down(v, 32);
                v += __shfl_down(v, 16);
                acc[b][j] = v;
            }
        __syncthreads();                          // all weight reads done -> alias sc
        float* part = sc;                         // part[((q*4+kqi)*8+b)*64 + d]
        if (lane < 16) {
            #pragma unroll
            for (int b = 0; b < 8; b++) {
                float4 o; o.x = acc[b][0]; o.y = acc[b][1]; o.z = acc[b][2]; o.w = acc[b][3];
                *(float4*)&part[(((q * 4 + kqi) * 8) + b) * 64 + d4 * 4] = o;
            }
        }
        __syncthreads();
        for (int i = t; i < 1024; i += 512) {
            int d = i & 63; int bq = i >> 6; int b = bq & 7; int q2 = bq >> 3;
            float s = part[((q2 * 4 + 0) * 8 + b) * 64 + d] +
                      part[((q2 * 4 + 1) * 8 + b) * 64 + d] +
                      part[((q2 * 4 + 2) * 8 + b) * 64 + d] +
                      part[((q2 * 4 + 3) * 8 + b) * 64 + d];
            out[((size_t)b * L_ + q0 + q2) * D_ + d] = s;
        }
    }
}

extern "C" void kernel_launch(void* const* d_in, const int* in_sizes, int n_in,
                              void* d_out, int out_size, void* d_ws, size_t ws_size,
                              hipStream_t stream)
{
    const float* query = (const float*)d_in[0];
    const float* key   = (const float*)d_in[1];
    const float* value = (const float*)d_in[2];
    const float* kb    = (const float*)d_in[3];
    const float* vb    = (const float*)d_in[4];
    const float* Wq    = (const float*)d_in[5];
    const float* bq    = (const float*)d_in[6];
    const float* Wk    = (const float*)d_in[7];
    const float* bk    = (const float*)d_in[8];
    const float* Wv    = (const float*)d_in[9];
    const float* bv    = (const float*)d_in[10];
    const int*   mask  = (const int*)d_in[11];
    float* out = (float*)d_out;

    const size_t PROJ = (size_t)B_ * L_ * D_;          // 524288 elements
    unsigned short* qhi = (unsigned short*)d_ws;
    unsigned short* qlo = qhi + PROJ;
    unsigned short* khi = qlo + PROJ;
    unsigned short* klo = khi + PROJ;
    float*          vp  = (float*)(klo + PROJ);        // 16B-aligned (4 MiB offset)

    proj_kernel<<<dim3(128, 3), 256, 0, stream>>>(query, key, value,
                                                  Wq, bq, Wk, bk, Wv, bv,
                                                  qhi, qlo, khi, klo, vp);
    mega_kernel<<<512, 512, 0, stream>>>(kb, vb, vp, qhi, qlo, khi, klo, mask, out);
}

// Round 2
// 690.396 us; speedup vs baseline: 2.2631x; 2.2631x over previous
//
#include <hip/hip_runtime.h>

#define B_ 8
#define L_ 1024
#define HID_ 1024
#define D_ 64

typedef short bf16x8 __attribute__((ext_vector_type(8)));
typedef float f32x4 __attribute__((ext_vector_type(4)));

__device__ inline short f2bf(float f) {
    unsigned u = __builtin_bit_cast(unsigned, f);
    unsigned r = (u + 0x7fffu + ((u >> 16) & 1u)) >> 16;   // RNE
    return (short)r;
}

// ---------------- K1: projections  out[r][d] = sum_h in[r][h]*W[h][d] + bias[d]
__global__ __launch_bounds__(256) void proj_kernel(
    const float* __restrict__ query, const float* __restrict__ key, const float* __restrict__ value,
    const float* __restrict__ Wq, const float* __restrict__ bq,
    const float* __restrict__ Wk, const float* __restrict__ bk,
    const float* __restrict__ Wv, const float* __restrict__ bv,
    float* __restrict__ qp, float* __restrict__ kp, float* __restrict__ vp)
{
    const int which = blockIdx.y;
    const float* in   = which == 0 ? query : (which == 1 ? key : value);
    const float* W    = which == 0 ? Wq : (which == 1 ? Wk : Wv);
    const float* bias = which == 0 ? bq : (which == 1 ? bk : bv);
    float* out        = which == 0 ? qp : (which == 1 ? kp : vp);

    __shared__ float Xs[64][68];
    __shared__ float Ws[64][64];

    const int t  = threadIdx.x;
    const int tx = t & 15;
    const int ty = t >> 4;
    const int r0 = blockIdx.x * 64;

    float acc[4][4] = {};
    for (int kk = 0; kk < HID_; kk += 64) {
        {
            const int r  = t >> 4;
            const int c4 = t & 15;
            #pragma unroll
            for (int i = 0; i < 4; i++) {
                float4 x = *(const float4*)(in + (size_t)(r0 + r + 16 * i) * HID_ + kk + 4 * c4);
                *(float4*)(&Xs[r + 16 * i][4 * c4]) = x;
                float4 w = *(const float4*)(W + (size_t)(kk + r + 16 * i) * D_ + 4 * c4);
                *(float4*)(&Ws[r + 16 * i][4 * c4]) = w;
            }
        }
        __syncthreads();
        #pragma unroll 8
        for (int k = 0; k < 64; k++) {
            float4 b4 = *(const float4*)(&Ws[k][4 * tx]);
            #pragma unroll
            for (int i = 0; i < 4; i++) {
                float a = Xs[4 * ty + i][k];
                acc[i][0] += a * b4.x;
                acc[i][1] += a * b4.y;
                acc[i][2] += a * b4.z;
                acc[i][3] += a * b4.w;
            }
        }
        __syncthreads();
    }
    float4 bb = *(const float4*)(bias + 4 * tx);
    #pragma unroll
    for (int i = 0; i < 4; i++) {
        float4 o;
        o.x = acc[i][0] + bb.x; o.y = acc[i][1] + bb.y;
        o.z = acc[i][2] + bb.z; o.w = acc[i][3] + bb.w;
        *(float4*)(out + (size_t)(r0 + 4 * ty + i) * D_ + 4 * tx) = o;
    }
}

// ---------------- K2: s1[b][q][k] = (qp[b,q,:]·kp[b,k,:])*0.125, masked  (fp32)
__global__ __launch_bounds__(256) void attn1_kernel(
    const float* __restrict__ qp, const float* __restrict__ kp,
    const int* __restrict__ mask, float* __restrict__ s1)
{
    const int b  = blockIdx.z;
    const int q0 = blockIdx.y * 128;
    const int k0 = blockIdx.x * 128;
    __shared__ float qs[128][68];
    __shared__ float ks[128][68];
    const int t = threadIdx.x;
    {
        const int row = t >> 4;
        const int c4  = t & 15;
        #pragma unroll
        for (int i = 0; i < 8; i++) {
            int r = row + 16 * i;
            *(float4*)&qs[r][c4 * 4] = *(const float4*)(qp + ((size_t)b * L_ + q0 + r) * D_ + c4 * 4);
            *(float4*)&ks[r][c4 * 4] = *(const float4*)(kp + ((size_t)b * L_ + k0 + r) * D_ + c4 * 4);
        }
    }
    __syncthreads();
    const int tx = t & 15, ty = t >> 4;
    float acc[8][8] = {};
    for (int d4 = 0; d4 < 16; d4++) {
        float4 qv[8], kv[8];
        #pragma unroll
        for (int i = 0; i < 8; i++) qv[i] = *(const float4*)&qs[ty + 16 * i][d4 * 4];
        #pragma unroll
        for (int j = 0; j < 8; j++) kv[j] = *(const float4*)&ks[tx + 16 * j][d4 * 4];
        #pragma unroll
        for (int i = 0; i < 8; i++)
            #pragma unroll
            for (int j = 0; j < 8; j++)
                acc[i][j] += qv[i].x * kv[j].x + qv[i].y * kv[j].y +
                             qv[i].z * kv[j].z + qv[i].w * kv[j].w;
    }
    #pragma unroll
    for (int j = 0; j < 8; j++) {
        int kg = k0 + tx + 16 * j;
        bool live = mask[b * L_ + kg] != 0;
        #pragma unroll
        for (int i = 0; i < 8; i++) {
            int qg = q0 + ty + 16 * i;
            s1[((size_t)b * L_ + qg) * L_ + kg] = live ? acc[i][j] * 0.125f : -1e9f;
        }
    }
}

// ---------------- K3: fused attn2(MFMA-bf16) + s1-add + softmax + vb-term
// grid 512 (2 q per block), block 512 (8 waves).
// Softmaxed weights are written back IN-PLACE over s1 (each block owns its
// 2 q rows exclusively), consumed later by pv_kernel.  out gets the vb term
// (exclusive ownership, no atomics).  LDS 70KB -> 2 blocks/CU.
#define KS_ 1032
__global__ __launch_bounds__(512) void row_kernel(
    const float* __restrict__ qp, const float* __restrict__ kb,
    const float* __restrict__ vb, float* __restrict__ s1w,
    float* __restrict__ out)
{
    __shared__ float sc[2 * 8 * KS_];     // [q][b][k] scores; later aliased for partials
    __shared__ short qbf[2 * 16 * 64];    // [q][b(16, 8..15 zero)][d] bf16, pre-scaled 0.125
    const int t = threadIdx.x;
    const int wave = t >> 6, lane = t & 63;
    const int q0 = blockIdx.x * 2;

    // prologue: scaled-bf16 q vectors
    #pragma unroll
    for (int i = 0; i < 4; i++) {
        int idx = t + 512 * i;            // 0..2047
        int d = idx & 63, bq = idx >> 6;
        int b = bq & 15, q = bq >> 4;
        float v = (b < 8) ? 0.125f * qp[((size_t)b * L_ + q0 + q) * D_ + d] : 0.0f;
        qbf[idx] = f2bf(v);
    }
    __syncthreads();

    // phase A1: s2 = q·kb^T via MFMA, kb fragments straight from global
    for (int job = wave; job < 128; job += 8) {
        int q = job >> 6, kt = job & 63;
        int k0 = kt * 16;
        const float* abase = kb + ((size_t)(q0 + q) * L_ + k0 + (lane & 15)) * D_ + (lane >> 4) * 8;
        f32x4 acc = {0.f, 0.f, 0.f, 0.f};
        #pragma unroll
        for (int h = 0; h < 2; h++) {
            float4 x0 = *(const float4*)(abase + h * 32);
            float4 x1 = *(const float4*)(abase + h * 32 + 4);
            bf16x8 a;
            a[0] = f2bf(x0.x); a[1] = f2bf(x0.y); a[2] = f2bf(x0.z); a[3] = f2bf(x0.w);
            a[4] = f2bf(x1.x); a[5] = f2bf(x1.y); a[6] = f2bf(x1.z); a[7] = f2bf(x1.w);
            bf16x8 bq = *(const bf16x8*)&qbf[(q * 16 + (lane & 15)) * 64 + h * 32 + (lane >> 4) * 8];
            acc = __builtin_amdgcn_mfma_f32_16x16x32_bf16(a, bq, acc, 0, 0, 0);
        }
        int b = lane & 15;
        if (b < 8) {
            float* dst = &sc[(q * 8 + b) * KS_ + k0 + (lane >> 4) * 4];
            dst[0] = acc[0]; dst[1] = acc[1]; dst[2] = acc[2]; dst[3] = acc[3];
        }
    }
    __syncthreads();

    // phase A2: += s1
    #pragma unroll
    for (int i = 0; i < 8; i++) {
        int idx = t + 512 * i;            // 0..4095 float4s
        int c4 = idx & 255;
        int row = idx >> 8;
        int b = row & 7, q = row >> 3;
        float4 s = *(const float4*)(s1w + ((size_t)b * L_ + q0 + q) * L_ + c4 * 4);
        float* dst = &sc[(q * 8 + b) * KS_ + c4 * 4];
        float4 cur = *(float4*)dst;
        cur.x += s.x; cur.y += s.y; cur.z += s.z; cur.w += s.w;
        *(float4*)dst = cur;
    }
    __syncthreads();

    // phase B: softmax per (q,b) row inside one wave; write w back over s1
    for (int r = wave; r < 16; r += 8) {
        int q = r >> 3, b = r & 7;
        float* rowp = &sc[r * KS_];
        float* wrow = s1w + ((size_t)b * L_ + q0 + q) * L_;
        float4 x[4];
        float m = -1e30f;
        #pragma unroll
        for (int j = 0; j < 4; j++) {
            x[j] = *(const float4*)&rowp[lane * 4 + 256 * j];
            m = fmaxf(m, fmaxf(fmaxf(x[j].x, x[j].y), fmaxf(x[j].z, x[j].w)));
        }
        #pragma unroll
        for (int off = 32; off; off >>= 1) m = fmaxf(m, __shfl_xor(m, off));
        float s = 0.f;
        #pragma unroll
        for (int j = 0; j < 4; j++) {
            x[j].x = __expf(x[j].x - m); x[j].y = __expf(x[j].y - m);
            x[j].z = __expf(x[j].z - m); x[j].w = __expf(x[j].w - m);
            s += x[j].x + x[j].y + x[j].z + x[j].w;
        }
        #pragma unroll
        for (int off = 32; off; off >>= 1) s += __shfl_xor(s, off);
        float inv = 1.0f / s;
        #pragma unroll
        for (int j = 0; j < 4; j++) {
            x[j].x *= inv; x[j].y *= inv; x[j].z *= inv; x[j].w *= inv;
            *(float4*)&rowp[lane * 4 + 256 * j] = x[j];
            *(float4*)&wrow[lane * 4 + 256 * j] = x[j];
        }
    }
    __syncthreads();

    // phase C: vb term only.  wave -> (q, k-quarter); lane = (kl=lane>>4, d4=lane&15)
    {
        const int q  = wave >> 2;
        const int kqi = wave & 3;
        const int kq = kqi * 256;
        const int kl = lane >> 4;
        const int d4 = lane & 15;
        float acc[8][4] = {};
        const float* vbbase = vb + ((size_t)(q0 + q) * L_ + kq + kl) * D_ + d4 * 4;
        #pragma unroll 4
        for (int j = 0; j < 64; j++) {
            int k = kq + j * 4 + kl;
            float4 vb4 = *(const float4*)(vbbase + (size_t)j * 4 * D_);
            #pragma unroll
            for (int b = 0; b < 8; b++) {
                float wgt = sc[(q * 8 + b) * KS_ + k];
                acc[b][0] += wgt * vb4.x;
                acc[b][1] += wgt * vb4.y;
                acc[b][2] += wgt * vb4.z;
                acc[b][3] += wgt * vb4.w;
            }
        }
        #pragma unroll
        for (int b = 0; b < 8; b++)
            #pragma unroll
            for (int j = 0; j < 4; j++) {
                float v = acc[b][j];
                v += __shfl_down(v, 32);
                v += __shfl_down(v, 16);
                acc[b][j] = v;
            }
        __syncthreads();                 // all sc weight reads done -> safe to alias
        float* part = sc;                // part[((q*4+kqi)*8+b)*64 + d]
        if (lane < 16) {
            #pragma unroll
            for (int b = 0; b < 8; b++) {
                float4 o; o.x = acc[b][0]; o.y = acc[b][1]; o.z = acc[b][2]; o.w = acc[b][3];
                *(float4*)&part[(((q * 4 + kqi) * 8) + b) * 64 + d4 * 4] = o;
            }
        }
        __syncthreads();
        for (int i = t; i < 1024; i += 512) {
            int d = i & 63; int bq = i >> 6; int b = bq & 7; int q2 = bq >> 3;
            float s = part[((q2 * 4 + 0) * 8 + b) * 64 + d] +
                      part[((q2 * 4 + 1) * 8 + b) * 64 + d] +
                      part[((q2 * 4 + 2) * 8 + b) * 64 + d] +
                      part[((q2 * 4 + 3) * 8 + b) * 64 + d];
            out[((size_t)b * L_ + q0 + q2) * D_ + d] = s;
        }
    }
}

// ---------------- K4: out[b][q][d] += sum_k w[b][q][k]*vp[b][k][d]
// 16-q tiles, grid (64,8)=512 blocks -> 2 blocks/CU (round-0 was 256 blocks
// = 1/CU, grid-limited).  Same k-accumulation order -> bitwise-identical out.
__global__ __launch_bounds__(256) void pv_kernel(
    const float* __restrict__ w, const float* __restrict__ vp, float* __restrict__ out)
{
    const int b  = blockIdx.y;
    const int q0 = blockIdx.x * 16;
    __shared__ float ws_[16][68];
    __shared__ float vs[64][64];
    const int t  = threadIdx.x;
    const int tx = t & 15;
    const int ty = t >> 4;
    float acc[4] = {};
    for (int kk = 0; kk < L_; kk += 64) {
        {
            int qi = t >> 4, kc = t & 15;
            float4 x = *(const float4*)(w + ((size_t)b * L_ + q0 + qi) * L_ + kk + 4 * kc);
            *(float4*)(&ws_[qi][4 * kc]) = x;
        }
        #pragma unroll
        for (int i = 0; i < 4; i++) {
            int f4 = t + 256 * i;
            int kr = f4 >> 4, dc = f4 & 15;
            float4 x = *(const float4*)(vp + ((size_t)b * L_ + kk + kr) * D_ + 4 * dc);
            *(float4*)(&vs[kr][4 * dc]) = x;
        }
        __syncthreads();
        #pragma unroll 8
        for (int k = 0; k < 64; k++) {
            float4 v4 = *(const float4*)(&vs[k][4 * tx]);
            float a = ws_[ty][k];
            acc[0] += a * v4.x; acc[1] += a * v4.y;
            acc[2] += a * v4.z; acc[3] += a * v4.w;
        }
        __syncthreads();
    }
    float* dst = out + ((size_t)b * L_ + q0 + ty) * D_ + 4 * tx;
    float4 o = *(const float4*)dst;
    o.x += acc[0]; o.y += acc[1]; o.z += acc[2]; o.w += acc[3];
    *(float4*)dst = o;
}

extern "C" void kernel_launch(void* const* d_in, const int* in_sizes, int n_in,
                              void* d_out, int out_size, void* d_ws, size_t ws_size,
                              hipStream_t stream)
{
    const float* query = (const float*)d_in[0];
    const float* key   = (const float*)d_in[1];
    const float* value = (const float*)d_in[2];
    const float* kb    = (const float*)d_in[3];
    const float* vb    = (const float*)d_in[4];
    const float* Wq    = (const float*)d_in[5];
    const float* bq    = (const float*)d_in[6];
    const float* Wk    = (const float*)d_in[7];
    const float* bk    = (const float*)d_in[8];
    const float* Wv    = (const float*)d_in[9];
    const float* bv    = (const float*)d_in[10];
    const int*   mask  = (const int*)d_in[11];
    float* out = (float*)d_out;

    float* ws = (float*)d_ws;
    const size_t PROJ = (size_t)B_ * L_ * D_;
    float* qp = ws;
    float* kp = ws + PROJ;
    float* vp = ws + 2 * PROJ;
    float* s1 = ws + 3 * PROJ;            // 32MB; becomes w after row_kernel

    proj_kernel<<<dim3(128, 3), 256, 0, stream>>>(query, key, value,
                                                  Wq, bq, Wk, bk, Wv, bv,
                                                  qp, kp, vp);
    attn1_kernel<<<dim3(8, 8, 8), 256, 0, stream>>>(qp, kp, mask, s1);
    row_kernel<<<512, 512, 0, stream>>>(qp, kb, vb, s1, out);
    pv_kernel<<<dim3(64, 8), 256, 0, stream>>>(s1, vp, out);
}

// Round 3
// 684.940 us; speedup vs baseline: 2.2811x; 1.0080x over previous
//
#include <hip/hip_runtime.h>

#define B_ 8
#define L_ 1024
#define HID_ 1024
#define D_ 64

typedef short bf16x8 __attribute__((ext_vector_type(8)));
typedef float f32x4 __attribute__((ext_vector_type(4)));

__device__ inline short f2bf(float f) {
    unsigned u = __builtin_bit_cast(unsigned, f);
    unsigned r = (u + 0x7fffu + ((u >> 16) & 1u)) >> 16;   // RNE
    return (short)r;
}
__device__ inline float bf2f(short h) {
    unsigned u = ((unsigned)(unsigned short)h) << 16;
    return __builtin_bit_cast(float, u);
}

// ---------------- K0: W -> bf16 hi/lo, pre-swizzled into MFMA B-fragment order.
// Slot layout per 'which': ((n*32+ks)*64 + lane)*8 + j  maps to
//   W[k = ks*32 + (lane>>4)*8 + j][d = n*16 + (lane&15)]
// so proj's B-load is one coalesced 16B read per (n,ks,lane).
__global__ __launch_bounds__(256) void wconv_kernel(
    const float* __restrict__ Wq, const float* __restrict__ Wk, const float* __restrict__ Wv,
    unsigned short* __restrict__ whi, unsigned short* __restrict__ wlo)
{
    int t = blockIdx.x * 256 + threadIdx.x;          // 0..196607 (3 * 65536)
    int which = t >> 16;
    int rem = t & 65535;
    int j = rem & 7, lane = (rem >> 3) & 63, ks = (rem >> 9) & 31, n = rem >> 14;
    int k = ks * 32 + (lane >> 4) * 8 + j;
    int d = n * 16 + (lane & 15);
    const float* W = which == 0 ? Wq : (which == 1 ? Wk : Wv);
    float v = W[k * D_ + d];
    short h = f2bf(v);
    whi[t] = (unsigned short)h;
    wlo[t] = (unsigned short)f2bf(v - bf2f(h));
}

// ---------------- K1: projections via MFMA hi/lo bf16 (fp32-accurate, ~2^-17).
// Block = 64 rows x 64 cols, 4 waves (16 rows each), K=1024.  No LDS, no barriers:
// A-fragments straight from global fp32 (X read exactly once, in-register hi/lo
// split), B-fragments are single 16B loads from the L2-resident wconv output.
__global__ __launch_bounds__(256) void proj_kernel(
    const float* __restrict__ query, const float* __restrict__ key, const float* __restrict__ value,
    const float* __restrict__ bq, const float* __restrict__ bk, const float* __restrict__ bv,
    const unsigned short* __restrict__ whi, const unsigned short* __restrict__ wlo,
    float* __restrict__ qp, float* __restrict__ kp, float* __restrict__ vp)
{
    const int blk = blockIdx.x;
    const int which = blk >> 7;                      // 128 blocks per operand
    const int r0 = (blk & 127) * 64;
    const float* in   = which == 0 ? query : (which == 1 ? key : value);
    const float* bias = which == 0 ? bq : (which == 1 ? bk : bv);
    float* out        = which == 0 ? qp : (which == 1 ? kp : vp);
    const unsigned short* wh = whi + (size_t)which * 65536;
    const unsigned short* wl = wlo + (size_t)which * 65536;

    const int wave = threadIdx.x >> 6, lane = threadIdx.x & 63;
    const int lr = lane & 15, lg = lane >> 4;

    // A[m = lr][k = ks*32 + lg*8 + j] = X[r0 + wave*16 + lr][...]
    const float* arow = in + (size_t)(r0 + wave * 16 + lr) * HID_ + lg * 8;

    f32x4 acc[4];
    #pragma unroll
    for (int n = 0; n < 4; n++) acc[n] = (f32x4){0.f, 0.f, 0.f, 0.f};

    #pragma unroll 2
    for (int ks = 0; ks < 32; ks++) {
        float4 x0 = *(const float4*)(arow + ks * 32);
        float4 x1 = *(const float4*)(arow + ks * 32 + 4);
        bf16x8 ahi, alo;
        {
            float xs0 = x0.x, xs1 = x0.y, xs2 = x0.z, xs3 = x0.w;
            float xs4 = x1.x, xs5 = x1.y, xs6 = x1.z, xs7 = x1.w;
            short h;
            h = f2bf(xs0); ahi[0] = h; alo[0] = f2bf(xs0 - bf2f(h));
            h = f2bf(xs1); ahi[1] = h; alo[1] = f2bf(xs1 - bf2f(h));
            h = f2bf(xs2); ahi[2] = h; alo[2] = f2bf(xs2 - bf2f(h));
            h = f2bf(xs3); ahi[3] = h; alo[3] = f2bf(xs3 - bf2f(h));
            h = f2bf(xs4); ahi[4] = h; alo[4] = f2bf(xs4 - bf2f(h));
            h = f2bf(xs5); ahi[5] = h; alo[5] = f2bf(xs5 - bf2f(h));
            h = f2bf(xs6); ahi[6] = h; alo[6] = f2bf(xs6 - bf2f(h));
            h = f2bf(xs7); ahi[7] = h; alo[7] = f2bf(xs7 - bf2f(h));
        }
        #pragma unroll
        for (int n = 0; n < 4; n++) {
            const size_t fo = ((size_t)(n * 32 + ks) * 64 + lane) * 8;
            bf16x8 bhi = *(const bf16x8*)(wh + fo);
            bf16x8 blo = *(const bf16x8*)(wl + fo);
            acc[n] = __builtin_amdgcn_mfma_f32_16x16x32_bf16(ahi, bhi, acc[n], 0, 0, 0);
            acc[n] = __builtin_amdgcn_mfma_f32_16x16x32_bf16(alo, bhi, acc[n], 0, 0, 0);
            acc[n] = __builtin_amdgcn_mfma_f32_16x16x32_bf16(ahi, blo, acc[n], 0, 0, 0);
        }
    }
    // D[row = lg*4+i][col = lr] per 16x16 tile n  (same mapping as row_kernel A1)
    #pragma unroll
    for (int n = 0; n < 4; n++) {
        float bv_ = bias[n * 16 + lr];
        #pragma unroll
        for (int i = 0; i < 4; i++) {
            out[(size_t)(r0 + wave * 16 + lg * 4 + i) * D_ + n * 16 + lr] = acc[n][i] + bv_;
        }
    }
}

// ---------------- K2: s1[b][q][k] = (qp[b,q,:]·kp[b,k,:])*0.125, masked  (fp32)
__global__ __launch_bounds__(256) void attn1_kernel(
    const float* __restrict__ qp, const float* __restrict__ kp,
    const int* __restrict__ mask, float* __restrict__ s1)
{
    const int b  = blockIdx.z;
    const int q0 = blockIdx.y * 128;
    const int k0 = blockIdx.x * 128;
    __shared__ float qs[128][68];
    __shared__ float ks[128][68];
    const int t = threadIdx.x;
    {
        const int row = t >> 4;
        const int c4  = t & 15;
        #pragma unroll
        for (int i = 0; i < 8; i++) {
            int r = row + 16 * i;
            *(float4*)&qs[r][c4 * 4] = *(const float4*)(qp + ((size_t)b * L_ + q0 + r) * D_ + c4 * 4);
            *(float4*)&ks[r][c4 * 4] = *(const float4*)(kp + ((size_t)b * L_ + k0 + r) * D_ + c4 * 4);
        }
    }
    __syncthreads();
    const int tx = t & 15, ty = t >> 4;
    float acc[8][8] = {};
    for (int d4 = 0; d4 < 16; d4++) {
        float4 qv[8], kv[8];
        #pragma unroll
        for (int i = 0; i < 8; i++) qv[i] = *(const float4*)&qs[ty + 16 * i][d4 * 4];
        #pragma unroll
        for (int j = 0; j < 8; j++) kv[j] = *(const float4*)&ks[tx + 16 * j][d4 * 4];
        #pragma unroll
        for (int i = 0; i < 8; i++)
            #pragma unroll
            for (int j = 0; j < 8; j++)
                acc[i][j] += qv[i].x * kv[j].x + qv[i].y * kv[j].y +
                             qv[i].z * kv[j].z + qv[i].w * kv[j].w;
    }
    #pragma unroll
    for (int j = 0; j < 8; j++) {
        int kg = k0 + tx + 16 * j;
        bool live = mask[b * L_ + kg] != 0;
        #pragma unroll
        for (int i = 0; i < 8; i++) {
            int qg = q0 + ty + 16 * i;
            s1[((size_t)b * L_ + qg) * L_ + kg] = live ? acc[i][j] * 0.125f : -1e9f;
        }
    }
}

// ---------------- K3: fused attn2(MFMA-bf16) + s1-add + softmax + vb-term
#define KS_ 1032
__global__ __launch_bounds__(512) void row_kernel(
    const float* __restrict__ qp, const float* __restrict__ kb,
    const float* __restrict__ vb, float* __restrict__ s1w,
    float* __restrict__ out)
{
    __shared__ float sc[2 * 8 * KS_];     // [q][b][k] scores; later aliased for partials
    __shared__ short qbf[2 * 16 * 64];    // [q][b(16, 8..15 zero)][d] bf16, pre-scaled 0.125
    const int t = threadIdx.x;
    const int wave = t >> 6, lane = t & 63;
    const int q0 = blockIdx.x * 2;

    // prologue: scaled-bf16 q vectors
    #pragma unroll
    for (int i = 0; i < 4; i++) {
        int idx = t + 512 * i;            // 0..2047
        int d = idx & 63, bq = idx >> 6;
        int b = bq & 15, q = bq >> 4;
        float v = (b < 8) ? 0.125f * qp[((size_t)b * L_ + q0 + q) * D_ + d] : 0.0f;
        qbf[idx] = f2bf(v);
    }
    __syncthreads();

    // phase A1: s2 = q·kb^T via MFMA, kb fragments straight from global
    for (int job = wave; job < 128; job += 8) {
        int q = job >> 6, kt = job & 63;
        int k0 = kt * 16;
        const float* abase = kb + ((size_t)(q0 + q) * L_ + k0 + (lane & 15)) * D_ + (lane >> 4) * 8;
        f32x4 acc = {0.f, 0.f, 0.f, 0.f};
        #pragma unroll
        for (int h = 0; h < 2; h++) {
            float4 x0 = *(const float4*)(abase + h * 32);
            float4 x1 = *(const float4*)(abase + h * 32 + 4);
            bf16x8 a;
            a[0] = f2bf(x0.x); a[1] = f2bf(x0.y); a[2] = f2bf(x0.z); a[3] = f2bf(x0.w);
            a[4] = f2bf(x1.x); a[5] = f2bf(x1.y); a[6] = f2bf(x1.z); a[7] = f2bf(x1.w);
            bf16x8 bq = *(const bf16x8*)&qbf[(q * 16 + (lane & 15)) * 64 + h * 32 + (lane >> 4) * 8];
            acc = __builtin_amdgcn_mfma_f32_16x16x32_bf16(a, bq, acc, 0, 0, 0);
        }
        int b = lane & 15;
        if (b < 8) {
            float* dst = &sc[(q * 8 + b) * KS_ + k0 + (lane >> 4) * 4];
            dst[0] = acc[0]; dst[1] = acc[1]; dst[2] = acc[2]; dst[3] = acc[3];
        }
    }
    __syncthreads();

    // phase A2: += s1
    #pragma unroll
    for (int i = 0; i < 8; i++) {
        int idx = t + 512 * i;            // 0..4095 float4s
        int c4 = idx & 255;
        int row = idx >> 8;
        int b = row & 7, q = row >> 3;
        float4 s = *(const float4*)(s1w + ((size_t)b * L_ + q0 + q) * L_ + c4 * 4);
        float* dst = &sc[(q * 8 + b) * KS_ + c4 * 4];
        float4 cur = *(float4*)dst;
        cur.x += s.x; cur.y += s.y; cur.z += s.z; cur.w += s.w;
        *(float4*)dst = cur;
    }
    __syncthreads();

    // phase B: softmax per (q,b) row inside one wave; write w back over s1
    for (int r = wave; r < 16; r += 8) {
        int q = r >> 3, b = r & 7;
        float* rowp = &sc[r * KS_];
        float* wrow = s1w + ((size_t)b * L_ + q0 + q) * L_;
        float4 x[4];
        float m = -1e30f;
        #pragma unroll
        for (int j = 0; j < 4; j++) {
            x[j] = *(const float4*)&rowp[lane * 4 + 256 * j];
            m = fmaxf(m, fmaxf(fmaxf(x[j].x, x[j].y), fmaxf(x[j].z, x[j].w)));
        }
        #pragma unroll
        for (int off = 32; off; off >>= 1) m = fmaxf(m, __shfl_xor(m, off));
        float s = 0.f;
        #pragma unroll
        for (int j = 0; j < 4; j++) {
            x[j].x = __expf(x[j].x - m); x[j].y = __expf(x[j].y - m);
            x[j].z = __expf(x[j].z - m); x[j].w = __expf(x[j].w - m);
            s += x[j].x + x[j].y + x[j].z + x[j].w;
        }
        #pragma unroll
        for (int off = 32; off; off >>= 1) s += __shfl_xor(s, off);
        float inv = 1.0f / s;
        #pragma unroll
        for (int j = 0; j < 4; j++) {
            x[j].x *= inv; x[j].y *= inv; x[j].z *= inv; x[j].w *= inv;
            *(float4*)&rowp[lane * 4 + 256 * j] = x[j];
            *(float4*)&wrow[lane * 4 + 256 * j] = x[j];
        }
    }
    __syncthreads();

    // phase C: vb term only.  wave -> (q, k-quarter); lane = (kl=lane>>4, d4=lane&15)
    {
        const int q  = wave >> 2;
        const int kqi = wave & 3;
        const int kq = kqi * 256;
        const int kl = lane >> 4;
        const int d4 = lane & 15;
        float acc[8][4] = {};
        const float* vbbase = vb + ((size_t)(q0 + q) * L_ + kq + kl) * D_ + d4 * 4;
        #pragma unroll 4
        for (int j = 0; j < 64; j++) {
            int k = kq + j * 4 + kl;
            float4 vb4 = *(const float4*)(vbbase + (size_t)j * 4 * D_);
            #pragma unroll
            for (int b = 0; b < 8; b++) {
                float wgt = sc[(q * 8 + b) * KS_ + k];
                acc[b][0] += wgt * vb4.x;
                acc[b][1] += wgt * vb4.y;
                acc[b][2] += wgt * vb4.z;
                acc[b][3] += wgt * vb4.w;
            }
        }
        #pragma unroll
        for (int b = 0; b < 8; b++)
            #pragma unroll
            for (int j = 0; j < 4; j++) {
                float v = acc[b][j];
                v += __shfl_down(v, 32);
                v += __shfl_down(v, 16);
                acc[b][j] = v;
            }
        __syncthreads();                 // all sc weight reads done -> safe to alias
        float* part = sc;                // part[((q*4+kqi)*8+b)*64 + d]
        if (lane < 16) {
            #pragma unroll
            for (int b = 0; b < 8; b++) {
                float4 o; o.x = acc[b][0]; o.y = acc[b][1]; o.z = acc[b][2]; o.w = acc[b][3];
                *(float4*)&part[(((q * 4 + kqi) * 8) + b) * 64 + d4 * 4] = o;
            }
        }
        __syncthreads();
        for (int i = t; i < 1024; i += 512) {
            int d = i & 63; int bq = i >> 6; int b = bq & 7; int q2 = bq >> 3;
            float s = part[((q2 * 4 + 0) * 8 + b) * 64 + d] +
                      part[((q2 * 4 + 1) * 8 + b) * 64 + d] +
                      part[((q2 * 4 + 2) * 8 + b) * 64 + d] +
                      part[((q2 * 4 + 3) * 8 + b) * 64 + d];
            out[((size_t)b * L_ + q0 + q2) * D_ + d] = s;
        }
    }
}

// ---------------- K4: out[b][q][d] += sum_k w[b][q][k]*vp[b][k][d]
__global__ __launch_bounds__(256) void pv_kernel(
    const float* __restrict__ w, const float* __restrict__ vp, float* __restrict__ out)
{
    const int b  = blockIdx.y;
    const int q0 = blockIdx.x * 16;
    __shared__ float ws_[16][68];
    __shared__ float vs[64][64];
    const int t  = threadIdx.x;
    const int tx = t & 15;
    const int ty = t >> 4;
    float acc[4] = {};
    for (int kk = 0; kk < L_; kk += 64) {
        {
            int qi = t >> 4, kc = t & 15;
            float4 x = *(const float4*)(w + ((size_t)b * L_ + q0 + qi) * L_ + kk + 4 * kc);
            *(float4*)(&ws_[qi][4 * kc]) = x;
        }
        #pragma unroll
        for (int i = 0; i < 4; i++) {
            int f4 = t + 256 * i;
            int kr = f4 >> 4, dc = f4 & 15;
            float4 x = *(const float4*)(vp + ((size_t)b * L_ + kk + kr) * D_ + 4 * dc);
            *(float4*)(&vs[kr][4 * dc]) = x;
        }
        __syncthreads();
        #pragma unroll 8
        for (int k = 0; k < 64; k++) {
            float4 v4 = *(const float4*)(&vs[k][4 * tx]);
            float a = ws_[ty][k];
            acc[0] += a * v4.x; acc[1] += a * v4.y;
            acc[2] += a * v4.z; acc[3] += a * v4.w;
        }
        __syncthreads();
    }
    float* dst = out + ((size_t)b * L_ + q0 + ty) * D_ + 4 * tx;
    float4 o = *(const float4*)dst;
    o.x += acc[0]; o.y += acc[1]; o.z += acc[2]; o.w += acc[3];
    *(float4*)dst = o;
}

extern "C" void kernel_launch(void* const* d_in, const int* in_sizes, int n_in,
                              void* d_out, int out_size, void* d_ws, size_t ws_size,
                              hipStream_t stream)
{
    const float* query = (const float*)d_in[0];
    const float* key   = (const float*)d_in[1];
    const float* value = (const float*)d_in[2];
    const float* kb    = (const float*)d_in[3];
    const float* vb    = (const float*)d_in[4];
    const float* Wq    = (const float*)d_in[5];
    const float* bq    = (const float*)d_in[6];
    const float* Wk    = (const float*)d_in[7];
    const float* bk    = (const float*)d_in[8];
    const float* Wv    = (const float*)d_in[9];
    const float* bv    = (const float*)d_in[10];
    const int*   mask  = (const int*)d_in[11];
    float* out = (float*)d_out;

    float* ws = (float*)d_ws;
    const size_t PROJ = (size_t)B_ * L_ * D_;          // 524288
    float* qp = ws;
    float* kp = ws + PROJ;
    float* vp = ws + 2 * PROJ;
    float* s1 = ws + 3 * PROJ;                         // 32MB; becomes w after row_kernel
    unsigned short* whi = (unsigned short*)(ws + 3 * PROJ + (size_t)B_ * L_ * L_);
    unsigned short* wlo = whi + 3 * 65536;

    wconv_kernel<<<768, 256, 0, stream>>>(Wq, Wk, Wv, whi, wlo);
    proj_kernel<<<384, 256, 0, stream>>>(query, key, value, bq, bk, bv, whi, wlo, qp, kp, vp);
    attn1_kernel<<<dim3(8, 8, 8), 256, 0, stream>>>(qp, kp, mask, s1);
    row_kernel<<<512, 512, 0, stream>>>(qp, kb, vb, s1, out);
    pv_kernel<<<dim3(64, 8), 256, 0, stream>>>(s1, vp, out);
}